// Round 2
// baseline (516.702 us; speedup 1.0000x reference)
//
#include <hip/hip_runtime.h>
#include <hip/hip_bf16.h>

#define TT 4096
#define DD 2048
#define NH 16
#define NKV 4
#define DHD 128
#define NQKV 3072

typedef __attribute__((ext_vector_type(8))) short short8;
typedef __attribute__((ext_vector_type(4))) float f32x4;
typedef __hip_bfloat16 bf16;

// async global->LDS, 16B per lane; LDS dest = wave-uniform base + lane*16
#define GLOAD_LDS16(g, l)                                                \
    __builtin_amdgcn_global_load_lds(                                    \
        (const __attribute__((address_space(1))) unsigned int*)(g),      \
        (__attribute__((address_space(3))) unsigned int*)(l), 16, 0, 0)

// ---------------- cast x -> bf16 ----------------
__global__ void cast_x_kernel(const float* __restrict__ x, bf16* __restrict__ xb, int n) {
    int i = (blockIdx.x * blockDim.x + threadIdx.x) * 4;
    if (i >= n) return;
    float4 v = *(const float4*)(x + i);
    xb[i + 0] = __float2bfloat16(v.x);
    xb[i + 1] = __float2bfloat16(v.y);
    xb[i + 2] = __float2bfloat16(v.z);
    xb[i + 3] = __float2bfloat16(v.w);
}

// ---------------- all 4 weight transposes in one launch ----------------
__global__ void transpose_cast_all(const float* __restrict__ Wq, const float* __restrict__ Wk,
                                   const float* __restrict__ Wv, const float* __restrict__ Wo,
                                   bf16* __restrict__ Wt, bf16* __restrict__ Wot) {
    __shared__ float tile[32][33];
    const float* in;
    bf16* out;
    int N, rowOff;
    switch (blockIdx.z) {
        case 0: in = Wq; out = Wt; N = 2048; rowOff = 0; break;
        case 1: in = Wk; out = Wt; N = 512; rowOff = 2048; break;
        case 2: in = Wv; out = Wt; N = 512; rowOff = 2560; break;
        default: in = Wo; out = Wot; N = 2048; rowOff = 0; break;
    }
    int n0 = blockIdx.y * 32;
    if (n0 >= N) return;
    int k0 = blockIdx.x * 32;
    int tx = threadIdx.x, ty = threadIdx.y;
#pragma unroll
    for (int i = 0; i < 4; ++i)
        tile[ty + i * 8][tx] = in[(size_t)(k0 + ty + i * 8) * N + n0 + tx];
    __syncthreads();
#pragma unroll
    for (int i = 0; i < 4; ++i)
        out[(size_t)(rowOff + n0 + ty + i * 8) * 2048 + k0 + tx] = __float2bfloat16(tile[tx][ty + i * 8]);
}

// ---------------- GEMM (m97 recipe): A (MxK) bf16, Bt (NxK) bf16, C (MxN) ----------------
template <bool OUT_BF16>
__global__ __launch_bounds__(256) void gemm_bt_kernel(const bf16* __restrict__ A,
                                                      const bf16* __restrict__ Bt,
                                                      void* __restrict__ C,
                                                      int M, int N, int K) {
    __shared__ bf16 As[128 * 32];
    __shared__ bf16 Bs[128 * 32];
    int bn0 = blockIdx.x * 128, bm0 = blockIdx.y * 128;
    int tid = threadIdx.x;
    int wave = tid >> 6, lane = tid & 63, quad = lane >> 4, l15 = lane & 15;
    int wm = (wave >> 1) * 64, wn = (wave & 1) * 64;

    // staging: per wave, 2 insts A (16 rows each) + 2 insts B
    int srow = wave * 32 + (lane >> 2);
    int scol = (lane & 3) * 8;
    const bf16* gA = A + (size_t)(bm0 + srow) * K + scol;
    const bf16* gB = Bt + (size_t)(bn0 + srow) * K + scol;
    bf16* lA = As + srow * 32 + scol;
    bf16* lB = Bs + srow * 32 + scol;

    f32x4 zero = {0.f, 0.f, 0.f, 0.f};
    f32x4 acc[4][4];
#pragma unroll
    for (int i = 0; i < 4; ++i)
#pragma unroll
        for (int j = 0; j < 4; ++j) acc[i][j] = zero;

    for (int k0 = 0; k0 < K; k0 += 32) {
        GLOAD_LDS16(gA + k0, lA);
        GLOAD_LDS16(gA + k0 + (size_t)16 * K, lA + 16 * 32);
        GLOAD_LDS16(gB + k0, lB);
        GLOAD_LDS16(gB + k0 + (size_t)16 * K, lB + 16 * 32);
        __syncthreads();
        short8 af[4], bfr[4];
#pragma unroll
        for (int i = 0; i < 4; ++i) af[i] = *(const short8*)&As[(wm + i * 16 + l15) * 32 + quad * 8];
#pragma unroll
        for (int j = 0; j < 4; ++j) bfr[j] = *(const short8*)&Bs[(wn + j * 16 + l15) * 32 + quad * 8];
#pragma unroll
        for (int i = 0; i < 4; ++i)
#pragma unroll
            for (int j = 0; j < 4; ++j)
                acc[i][j] = __builtin_amdgcn_mfma_f32_16x16x32_bf16(af[i], bfr[j], acc[i][j], 0, 0, 0);
        __syncthreads();
    }
#pragma unroll
    for (int i = 0; i < 4; ++i)
#pragma unroll
        for (int j = 0; j < 4; ++j)
#pragma unroll
            for (int r = 0; r < 4; ++r) {
                int row = bm0 + wm + i * 16 + quad * 4 + r;
                int col = bn0 + wn + j * 16 + l15;
                float v = acc[i][j][r];
                if (OUT_BF16)
                    ((bf16*)C)[(size_t)row * N + col] = __float2bfloat16(v);
                else
                    ((float*)C)[(size_t)row * N + col] = v;
            }
}

// ---------------- RoPE + head split. Q scaled by 1/sqrt(128)*log2(e) ----------------
__global__ void rope_split_kernel(const bf16* __restrict__ QKV, bf16* __restrict__ Qs,
                                  bf16* __restrict__ Ks, bf16* __restrict__ Vt) {
    int slot = blockIdx.x * 4 + (threadIdx.x >> 6);
    int d = threadIdx.x & 63;
    int t = slot / 24, c = slot % 24;
    const bf16* base = QKV + (size_t)t * NQKV;
    int off = (c < 16) ? c * 128 : (c < 20) ? 2048 + (c - 16) * 128 : 2560 + (c - 20) * 128;
    float x1 = __bfloat162float(base[off + d]);
    float x2 = __bfloat162float(base[off + 64 + d]);
    float o1, o2;
    if (c < 20) {
        float invf = __expf((float)d * -0.14391156831f);
        float ang = (float)t * invf;
        float sn = sinf(ang), cs = cosf(ang);
        o1 = x1 * cs - x2 * sn;
        o2 = x1 * sn + x2 * cs;
    } else {
        o1 = x1;
        o2 = x2;
    }
    if (c < 16) {
        const float scale = 0.12751741f;  // 1/sqrt(128) * log2(e)
        o1 *= scale;
        o2 *= scale;
        bf16* dst = Qs + ((size_t)c * TT + t) * DHD;
        dst[d] = __float2bfloat16(o1);
        dst[d + 64] = __float2bfloat16(o2);
    } else if (c < 20) {
        bf16* dst = Ks + ((size_t)(c - 16) * TT + t) * DHD;
        dst[d] = __float2bfloat16(o1);
        dst[d + 64] = __float2bfloat16(o2);
    } else {
        int gg = c - 20;
        Vt[((size_t)gg * DHD + d) * TT + t] = __float2bfloat16(o1);
        Vt[((size_t)gg * DHD + d + 64) * TT + t] = __float2bfloat16(o2);
    }
}

// ---------------- Flash attention: transposed-S, xor-swizzled LDS, split-KV ----------------
// 512 threads = 8 waves: group 0 (waves 0-3) handles EVEN k-tiles, group 1 (waves 4-7)
// handles ODD k-tiles of the same 64-row Q tile. Each group has its own K/V LDS region and
// private online-softmax state (m,l,acc); states are merged once per pass via LDS
// (flash split-K merge). Doubles resident waves/CU (8 -> 16) at exact causal balance:
// every block does 33 barrier-iterations. LDS = 80KB -> exactly 2 blocks/CU.
__global__ __launch_bounds__(512, 4) void attn_kernel(const bf16* __restrict__ Qs,
                                                      const bf16* __restrict__ Ks,
                                                      const bf16* __restrict__ Vt,
                                                      bf16* __restrict__ Y) {
    // layout (bytes):
    //   [0      , 32768 ) K0(64x128 swz) + V0(128x64 swz)   group 0
    //   [32768  , 65536 ) K1 + V1                            group 1
    //   [65536  , 81920 ) P per wave (8 x 16x64 swz)
    // merge-phase aliases (loop LDS dead then, separated by barriers):
    //   Obuf  = [32768, 66560)  f32 [4 pairs][16 qrow][132]  (pad +4 -> 2-way banks)
    //   mlbuf = [80896, 81920)  f32 [8 waves][16 qrow][2]
    __shared__ char smem[81920];
    int h = blockIdx.y, bpair = blockIdx.x, g = h >> 2;
    int tid = threadIdx.x, wave = tid >> 6, lane = tid & 63, quad = lane >> 4, l15 = lane & 15;
    int grp = wave >> 2;   // 0: even k-tiles, 1: odd k-tiles
    int w = wave & 3;      // q-subtile (16 rows) within the 64-row Q tile
    int gtid = tid & 255;  // tid within group

    bf16* KsL = (bf16*)(smem + grp * 32768);          // row=key(64), chunk c at c^(row&15)
    bf16* VtL = (bf16*)(smem + grp * 32768 + 16384);  // row=dh(128), chunk c at c^(row&7)
    bf16* PsW = (bf16*)(smem + 65536) + wave * (16 * 64);
    float* Obuf = (float*)(smem + 32768);
    float* mlbuf = (float*)(smem + 80896);

    const bf16* kg = Ks + (size_t)g * TT * DHD;
    const bf16* vg = Vt + (size_t)g * DHD * TT;
    f32x4 zero = {0.f, 0.f, 0.f, 0.f};

    for (int pass = 0; pass < 2; ++pass) {
        int qt = (pass == 0) ? bpair : 63 - bpair;
        int qbase = qt * 64 + w * 16;

        short8 qf[4];
        const bf16* qptr = Qs + ((size_t)h * TT + qbase + l15) * DHD + quad * 8;
#pragma unroll
        for (int ks = 0; ks < 4; ++ks) qf[ks] = *(const short8*)(qptr + ks * 32);

        f32x4 acc[8];
#pragma unroll
        for (int i = 0; i < 8; ++i) acc[i] = zero;
        float m_i = -1e30f, l_i = 0.f;

        int nIter = (qt >> 1) + 1;
        for (int it = 0; it < nIter; ++it) {
            int kt = it * 2 + grp;
            bool active = (kt <= qt);
            bool diag = (kt == qt);
            int kb = kt * 64;
            short8 kv[4], vv[4];
            int krow[4], kc[4], vrow[4], vc[4];
            if (active) {
#pragma unroll
                for (int r = 0; r < 4; ++r) {
                    int idx = r * 256 + gtid;
                    krow[r] = idx >> 4;
                    kc[r] = idx & 15;
                    kv[r] = *(const short8*)(kg + (size_t)(kb + krow[r]) * DHD + kc[r] * 8);
                    vrow[r] = idx >> 3;
                    vc[r] = idx & 7;
                    vv[r] = *(const short8*)(vg + (size_t)vrow[r] * TT + kb + vc[r] * 8);
                }
            }
            __syncthreads();  // prior iter LDS reads / merge-phase reads complete
            if (active) {
#pragma unroll
                for (int r = 0; r < 4; ++r) {
                    *(short8*)&KsL[krow[r] * 128 + ((kc[r] ^ (krow[r] & 15)) * 8)] = kv[r];
                    *(short8*)&VtL[vrow[r] * 64 + ((vc[r] ^ (vrow[r] & 7)) * 8)] = vv[r];
                }
            }
            __syncthreads();

            if (active) {
                // ---- S^T = K Q^T : A=K frag, B=Q frag ----
                f32x4 s[4];
#pragma unroll
                for (int nt = 0; nt < 4; ++nt) {
                    if (!diag || nt <= w) {
                        s[nt] = zero;
#pragma unroll
                        for (int ks = 0; ks < 4; ++ks) {
                            int ch = (ks * 4 + quad) ^ l15;
                            short8 kf = *(const short8*)&KsL[(nt * 16 + l15) * 128 + ch * 8];
                            s[nt] = __builtin_amdgcn_mfma_f32_16x16x32_bf16(kf, qf[ks], s[nt], 0, 0, 0);
                        }
                        if (diag && nt == w) {
#pragma unroll
                            for (int r = 0; r < 4; ++r)
                                if (quad * 4 + r > l15) s[nt][r] = -1e30f;
                        }
                    } else {
#pragma unroll
                        for (int r = 0; r < 4; ++r) s[nt][r] = -1e30f;
                    }
                }

                // ---- online softmax: state per lane (qrow = l15), base-2 ----
                float mloc = -1e30f;
#pragma unroll
                for (int nt = 0; nt < 4; ++nt)
#pragma unroll
                    for (int r = 0; r < 4; ++r) mloc = fmaxf(mloc, s[nt][r]);
                mloc = fmaxf(mloc, __shfl_xor(mloc, 16));
                mloc = fmaxf(mloc, __shfl_xor(mloc, 32));
                float mnew = fmaxf(m_i, mloc);
                bool up = __any(mloc > m_i);  // wave-uniform; skip rescale if max unchanged
                float alpha = up ? exp2f(m_i - mnew) : 1.0f;
                float sl = 0.f;
#pragma unroll
                for (int nt = 0; nt < 4; ++nt)
#pragma unroll
                    for (int r = 0; r < 4; ++r) {
                        s[nt][r] = exp2f(s[nt][r] - mnew);
                        sl += s[nt][r];
                    }
                sl += __shfl_xor(sl, 16);
                sl += __shfl_xor(sl, 32);
                l_i = l_i * alpha + sl;
                m_i = mnew;
                if (up) {
#pragma unroll
                    for (int d8 = 0; d8 < 8; ++d8)
#pragma unroll
                        for (int r = 0; r < 4; ++r) acc[d8][r] *= alpha;
                }

                // ---- P -> PsW[qrow=l15][key] (swizzled, paired b32 writes) ----
#pragma unroll
                for (int nt = 0; nt < 4; ++nt)
#pragma unroll
                    for (int rr = 0; rr < 2; ++rr) {
                        int col = nt * 16 + quad * 4 + rr * 2;
                        int ch = (col >> 3) ^ (l15 & 7);
                        __hip_bfloat162 pk;
                        pk.x = __float2bfloat16(s[nt][rr * 2]);
                        pk.y = __float2bfloat16(s[nt][rr * 2 + 1]);
                        *(__hip_bfloat162*)&PsW[l15 * 64 + ch * 8 + (col & 7)] = pk;
                    }
                asm volatile("s_waitcnt lgkmcnt(0)" ::: "memory");

                // ---- O^T += V^T P^T : A=Vt frag, B=P frag ----
                int kkmax = diag ? (w >> 1) + 1 : 2;
#pragma unroll
                for (int kk = 0; kk < 2; ++kk) {
                    if (kk < kkmax) {
                        int chp = (kk * 4 + quad) ^ (l15 & 7);
                        short8 pf = *(const short8*)&PsW[l15 * 64 + chp * 8];
#pragma unroll
                        for (int d8 = 0; d8 < 8; ++d8) {
                            short8 vf = *(const short8*)&VtL[(d8 * 16 + l15) * 64 + chp * 8];
                            acc[d8] = __builtin_amdgcn_mfma_f32_16x16x32_bf16(vf, pf, acc[d8], 0, 0, 0);
                        }
                    }
                }
            }
        }

        // ---- split-KV merge: group1 state folded into group0, then epilogue ----
        __syncthreads();  // loop LDS reads complete everywhere
        if (quad == 0) {
            mlbuf[(wave * 16 + l15) * 2] = m_i;
            mlbuf[(wave * 16 + l15) * 2 + 1] = l_i;
        }
        __syncthreads();
        if (grp == 1) {
            float m_a = mlbuf[(w * 16 + l15) * 2];
            float mm = fmaxf(m_a, m_i);
            float fb = exp2f(m_i - mm);
            float* ob = Obuf + (w * 16 + l15) * 132;
#pragma unroll
            for (int d8 = 0; d8 < 8; ++d8) {
                f32x4 t = acc[d8] * fb;
                *(f32x4*)&ob[d8 * 16 + quad * 4] = t;
            }
        }
        __syncthreads();
        if (grp == 0) {
            float m_b = mlbuf[((w + 4) * 16 + l15) * 2];
            float l_b = mlbuf[((w + 4) * 16 + l15) * 2 + 1];
            float mm = fmaxf(m_i, m_b);
            float fa = exp2f(m_i - mm);
            float fb = exp2f(m_b - mm);
            float lt = l_i * fa + l_b * fb;
            float* ob = Obuf + (w * 16 + l15) * 132;
#pragma unroll
            for (int d8 = 0; d8 < 8; ++d8) {
                f32x4 t = *(const f32x4*)&ob[d8 * 16 + quad * 4];
                acc[d8] = acc[d8] * fa + t;
            }
            float linv = 1.0f / lt;  // per lane (qrow = l15); lt >= diag term > 0

            // ---- epilogue: O^T -> (LDS transpose in K0 region) -> coalesced Y ----
            bf16* ow = (bf16*)smem + w * 2048;  // 16 rows (qrow) x 128 cols (dh), swizzled
#pragma unroll
            for (int d8 = 0; d8 < 8; ++d8)
#pragma unroll
                for (int rr = 0; rr < 2; ++rr) {
                    int colD = d8 * 16 + quad * 4 + rr * 2;
                    int ch = (colD >> 3) ^ (l15 & 7);
                    __hip_bfloat162 o2;
                    o2.x = __float2bfloat16(acc[d8][rr * 2] * linv);
                    o2.y = __float2bfloat16(acc[d8][rr * 2 + 1] * linv);
                    *(__hip_bfloat162*)&ow[l15 * 128 + ch * 8 + (colD & 7)] = o2;
                }
            asm volatile("s_waitcnt lgkmcnt(0)" ::: "memory");
#pragma unroll
            for (int c = 0; c < 4; ++c) {
                int chunk = quad * 4 + c;
                int ch = chunk ^ (l15 & 7);
                short8 ov = *(const short8*)&ow[l15 * 128 + ch * 8];
                *(short8*)&Y[(size_t)(qbase + l15) * DD + h * DHD + chunk * 8] = ov;
            }
        }
        __syncthreads();  // pass-2 staging must not clobber merge/epilogue reads
    }
}

extern "C" void kernel_launch(void* const* d_in, const int* in_sizes, int n_in,
                              void* d_out, int out_size, void* d_ws, size_t ws_size,
                              hipStream_t stream) {
    const float* x = (const float*)d_in[0];
    const float* Wq = (const float*)d_in[1];
    const float* Wk = (const float*)d_in[2];
    const float* Wv = (const float*)d_in[3];
    const float* Wo = (const float*)d_in[4];

    char* ws = (char*)d_ws;
    size_t off = 0;
    auto alloc = [&](size_t bytes) {
        void* p = ws + off;
        off += (bytes + 255) & ~(size_t)255;
        return p;
    };
    bf16* xb = (bf16*)alloc((size_t)TT * DD * 2);
    bf16* Wt = (bf16*)alloc((size_t)NQKV * DD * 2);
    bf16* Wot = (bf16*)alloc((size_t)DD * DD * 2);
    bf16* QKVb = (bf16*)alloc((size_t)TT * NQKV * 2);
    bf16* Qs = (bf16*)alloc((size_t)NH * TT * DHD * 2);
    bf16* Ksb = (bf16*)alloc((size_t)NKV * TT * DHD * 2);
    bf16* Vtb = (bf16*)alloc((size_t)NKV * DHD * TT * 2);
    bf16* Yb = (bf16*)alloc((size_t)TT * DD * 2);

    cast_x_kernel<<<(TT * DD / 4 + 255) / 256, 256, 0, stream>>>(x, xb, TT * DD);
    transpose_cast_all<<<dim3(64, 64, 4), dim3(32, 8), 0, stream>>>(Wq, Wk, Wv, Wo, Wt, Wot);

    gemm_bt_kernel<true><<<dim3(NQKV / 128, TT / 128), 256, 0, stream>>>(xb, Wt, QKVb, TT, NQKV, DD);
    rope_split_kernel<<<TT * 24 / 4, 256, 0, stream>>>(QKVb, Qs, Ksb, Vtb);
    attn_kernel<<<dim3(32, NH), 512, 0, stream>>>(Qs, Ksb, Vtb, Yb);
    gemm_bt_kernel<false><<<dim3(DD / 128, TT / 128), 256, 0, stream>>>(Yb, Wot, d_out, TT, DD, DD);
}

// Round 3
// 405.265 us; speedup vs baseline: 1.2750x; 1.2750x over previous
//
#include <hip/hip_runtime.h>
#include <hip/hip_bf16.h>

#define TT 4096
#define DD 2048
#define NH 16
#define NKV 4
#define DHD 128
#define NQKV 3072

typedef __attribute__((ext_vector_type(8))) short short8;
typedef __attribute__((ext_vector_type(4))) float f32x4;
typedef __hip_bfloat16 bf16;

// async global->LDS, 16B per lane; LDS dest = wave-uniform base + lane*16
#define GLOAD_LDS16(g, l)                                                \
    __builtin_amdgcn_global_load_lds(                                    \
        (const __attribute__((address_space(1))) unsigned int*)(g),      \
        (__attribute__((address_space(3))) unsigned int*)(l), 16, 0, 0)

// ---------------- cast x -> bf16 ----------------
__global__ void cast_x_kernel(const float* __restrict__ x, bf16* __restrict__ xb, int n) {
    int i = (blockIdx.x * blockDim.x + threadIdx.x) * 4;
    if (i >= n) return;
    float4 v = *(const float4*)(x + i);
    xb[i + 0] = __float2bfloat16(v.x);
    xb[i + 1] = __float2bfloat16(v.y);
    xb[i + 2] = __float2bfloat16(v.z);
    xb[i + 3] = __float2bfloat16(v.w);
}

// ---------------- all 4 weight transposes in one launch ----------------
__global__ void transpose_cast_all(const float* __restrict__ Wq, const float* __restrict__ Wk,
                                   const float* __restrict__ Wv, const float* __restrict__ Wo,
                                   bf16* __restrict__ Wt, bf16* __restrict__ Wot) {
    __shared__ float tile[32][33];
    const float* in;
    bf16* out;
    int N, rowOff;
    switch (blockIdx.z) {
        case 0: in = Wq; out = Wt; N = 2048; rowOff = 0; break;
        case 1: in = Wk; out = Wt; N = 512; rowOff = 2048; break;
        case 2: in = Wv; out = Wt; N = 512; rowOff = 2560; break;
        default: in = Wo; out = Wot; N = 2048; rowOff = 0; break;
    }
    int n0 = blockIdx.y * 32;
    if (n0 >= N) return;
    int k0 = blockIdx.x * 32;
    int tx = threadIdx.x, ty = threadIdx.y;
#pragma unroll
    for (int i = 0; i < 4; ++i)
        tile[ty + i * 8][tx] = in[(size_t)(k0 + ty + i * 8) * N + n0 + tx];
    __syncthreads();
#pragma unroll
    for (int i = 0; i < 4; ++i)
        out[(size_t)(rowOff + n0 + ty + i * 8) * 2048 + k0 + tx] = __float2bfloat16(tile[tx][ty + i * 8]);
}

// ---------------- GEMM (m97 recipe): A (MxK) bf16, Bt (NxK) bf16, C (MxN) ----------------
template <bool OUT_BF16>
__global__ __launch_bounds__(256) void gemm_bt_kernel(const bf16* __restrict__ A,
                                                      const bf16* __restrict__ Bt,
                                                      void* __restrict__ C,
                                                      int M, int N, int K) {
    __shared__ bf16 As[128 * 32];
    __shared__ bf16 Bs[128 * 32];
    int bn0 = blockIdx.x * 128, bm0 = blockIdx.y * 128;
    int tid = threadIdx.x;
    int wave = tid >> 6, lane = tid & 63, quad = lane >> 4, l15 = lane & 15;
    int wm = (wave >> 1) * 64, wn = (wave & 1) * 64;

    // staging: per wave, 2 insts A (16 rows each) + 2 insts B
    int srow = wave * 32 + (lane >> 2);
    int scol = (lane & 3) * 8;
    const bf16* gA = A + (size_t)(bm0 + srow) * K + scol;
    const bf16* gB = Bt + (size_t)(bn0 + srow) * K + scol;
    bf16* lA = As + srow * 32 + scol;
    bf16* lB = Bs + srow * 32 + scol;

    f32x4 zero = {0.f, 0.f, 0.f, 0.f};
    f32x4 acc[4][4];
#pragma unroll
    for (int i = 0; i < 4; ++i)
#pragma unroll
        for (int j = 0; j < 4; ++j) acc[i][j] = zero;

    for (int k0 = 0; k0 < K; k0 += 32) {
        GLOAD_LDS16(gA + k0, lA);
        GLOAD_LDS16(gA + k0 + (size_t)16 * K, lA + 16 * 32);
        GLOAD_LDS16(gB + k0, lB);
        GLOAD_LDS16(gB + k0 + (size_t)16 * K, lB + 16 * 32);
        __syncthreads();
        short8 af[4], bfr[4];
#pragma unroll
        for (int i = 0; i < 4; ++i) af[i] = *(const short8*)&As[(wm + i * 16 + l15) * 32 + quad * 8];
#pragma unroll
        for (int j = 0; j < 4; ++j) bfr[j] = *(const short8*)&Bs[(wn + j * 16 + l15) * 32 + quad * 8];
#pragma unroll
        for (int i = 0; i < 4; ++i)
#pragma unroll
            for (int j = 0; j < 4; ++j)
                acc[i][j] = __builtin_amdgcn_mfma_f32_16x16x32_bf16(af[i], bfr[j], acc[i][j], 0, 0, 0);
        __syncthreads();
    }
#pragma unroll
    for (int i = 0; i < 4; ++i)
#pragma unroll
        for (int j = 0; j < 4; ++j)
#pragma unroll
            for (int r = 0; r < 4; ++r) {
                int row = bm0 + wm + i * 16 + quad * 4 + r;
                int col = bn0 + wn + j * 16 + l15;
                float v = acc[i][j][r];
                if (OUT_BF16)
                    ((bf16*)C)[(size_t)row * N + col] = __float2bfloat16(v);
                else
                    ((float*)C)[(size_t)row * N + col] = v;
            }
}

// ---------------- RoPE + head split. Q scaled by 1/sqrt(128)*log2(e) ----------------
__global__ void rope_split_kernel(const bf16* __restrict__ QKV, bf16* __restrict__ Qs,
                                  bf16* __restrict__ Ks, bf16* __restrict__ Vt) {
    int slot = blockIdx.x * 4 + (threadIdx.x >> 6);
    int d = threadIdx.x & 63;
    int t = slot / 24, c = slot % 24;
    const bf16* base = QKV + (size_t)t * NQKV;
    int off = (c < 16) ? c * 128 : (c < 20) ? 2048 + (c - 16) * 128 : 2560 + (c - 20) * 128;
    float x1 = __bfloat162float(base[off + d]);
    float x2 = __bfloat162float(base[off + 64 + d]);
    float o1, o2;
    if (c < 20) {
        float invf = __expf((float)d * -0.14391156831f);
        float ang = (float)t * invf;
        float sn = sinf(ang), cs = cosf(ang);
        o1 = x1 * cs - x2 * sn;
        o2 = x1 * sn + x2 * cs;
    } else {
        o1 = x1;
        o2 = x2;
    }
    if (c < 16) {
        const float scale = 0.12751741f;  // 1/sqrt(128) * log2(e)
        o1 *= scale;
        o2 *= scale;
        bf16* dst = Qs + ((size_t)c * TT + t) * DHD;
        dst[d] = __float2bfloat16(o1);
        dst[d + 64] = __float2bfloat16(o2);
    } else if (c < 20) {
        bf16* dst = Ks + ((size_t)(c - 16) * TT + t) * DHD;
        dst[d] = __float2bfloat16(o1);
        dst[d + 64] = __float2bfloat16(o2);
    } else {
        int gg = c - 20;
        Vt[((size_t)gg * DHD + d) * TT + t] = __float2bfloat16(o1);
        Vt[((size_t)gg * DHD + d + 64) * TT + t] = __float2bfloat16(o2);
    }
}

// ---------------- Flash attention: transposed-S, xor-swizzled LDS, split-KV ----------------
// 512 threads = 8 waves: group 0 (waves 0-3) handles EVEN k-tiles, group 1 (waves 4-7)
// handles ODD k-tiles of the same 64-row Q tile; states merged once per pass (split-K merge).
// K/V staging is global_load_lds (rule #21: LINEAR LDS dest + inverse-swizzled GLOBAL source
// + swizzled reads) -- zero staging registers, no ds_writes. This removes the round-1 spill
// (WRITE_SIZE 322MB of scratch traffic at VGPR=64 with ~100 live regs).
__global__ __launch_bounds__(512, 4) void attn_kernel(const bf16* __restrict__ Qs,
                                                      const bf16* __restrict__ Ks,
                                                      const bf16* __restrict__ Vt,
                                                      bf16* __restrict__ Y) {
    // layout (bytes):
    //   [0      , 32768 ) K0(64x128 swz) + V0(128x64 swz)   group 0
    //   [32768  , 65536 ) K1 + V1                            group 1
    //   [65536  , 81920 ) P per wave (8 x 16x64 swz)
    // merge-phase aliases (loop LDS dead then, separated by barriers):
    //   Obuf  = [32768, 66560)  f32 [4 pairs][16 qrow][132]  (pad +4 -> 2-way banks)
    //   mlbuf = [80896, 81920)  f32 [8 waves][16 qrow][2]
    __shared__ char smem[81920];
    int h = blockIdx.y, bpair = blockIdx.x, g = h >> 2;
    int tid = threadIdx.x, wave = tid >> 6, lane = tid & 63, quad = lane >> 4, l15 = lane & 15;
    int grp = wave >> 2;   // 0: even k-tiles, 1: odd k-tiles
    int w = wave & 3;      // q-subtile (16 rows) within the 64-row Q tile
    int gtid = tid & 255;  // tid within group

    bf16* KsL = (bf16*)(smem + grp * 32768);          // row=key(64), chunk c holds global c^(row&15)
    bf16* VtL = (bf16*)(smem + grp * 32768 + 16384);  // row=dh(128), chunk c holds global c^(row&7)
    bf16* PsW = (bf16*)(smem + 65536) + wave * (16 * 64);
    float* Obuf = (float*)(smem + 32768);
    float* mlbuf = (float*)(smem + 80896);

    const bf16* kg = Ks + (size_t)g * TT * DHD;
    const bf16* vg = Vt + (size_t)g * DHD * TT;
    f32x4 zero = {0.f, 0.f, 0.f, 0.f};

    // loop-invariant per-lane staging geometry (inverse-swizzled global offsets, linear LDS)
    int koffl[4], voffl[4], ldsl[4];
#pragma unroll
    for (int r = 0; r < 4; ++r) {
        int idx = r * 256 + gtid;
        int krow = idx >> 4, kch = (idx & 15) ^ (krow & 15);
        koffl[r] = krow * DHD + kch * 8;
        int vrow = idx >> 3, vch = (idx & 7) ^ (vrow & 7);
        voffl[r] = vrow * TT + vch * 8;
        ldsl[r] = idx * 8;  // elements; *2B = r*4096 + wave*1024 + lane*16 (linear)
    }

    for (int pass = 0; pass < 2; ++pass) {
        int qt = (pass == 0) ? bpair : 63 - bpair;
        int qbase = qt * 64 + w * 16;

        short8 qf[4];
        const bf16* qptr = Qs + ((size_t)h * TT + qbase + l15) * DHD + quad * 8;
#pragma unroll
        for (int ks = 0; ks < 4; ++ks) qf[ks] = *(const short8*)(qptr + ks * 32);

        f32x4 acc[8];
#pragma unroll
        for (int i = 0; i < 8; ++i) acc[i] = zero;
        float m_i = -1e30f, l_i = 0.f;

        const bf16* kSrc = kg + (size_t)grp * 64 * DHD;  // k-tile kt = it*2+grp
        const bf16* vSrc = vg + grp * 64;
        int nIter = (qt >> 1) + 1;
        for (int it = 0; it < nIter; ++it) {
            int kt = it * 2 + grp;
            bool active = (kt <= qt);
            bool diag = (kt == qt);
            __syncthreads();  // prior iter LDS reads / merge-phase reads complete
            if (active) {
#pragma unroll
                for (int r = 0; r < 4; ++r) {
                    GLOAD_LDS16(kSrc + koffl[r], KsL + ldsl[r]);
                    GLOAD_LDS16(vSrc + voffl[r], VtL + ldsl[r]);
                }
            }
            kSrc += 128 * DHD;  // advance 2 k-tiles
            vSrc += 128;
            __syncthreads();  // drains vmcnt -> K/V visible to whole group

            if (active) {
                // ---- S^T = K Q^T : A=K frag, B=Q frag ----
                f32x4 s[4];
#pragma unroll
                for (int nt = 0; nt < 4; ++nt) {
                    if (!diag || nt <= w) {
                        s[nt] = zero;
#pragma unroll
                        for (int ks = 0; ks < 4; ++ks) {
                            int ch = (ks * 4 + quad) ^ l15;
                            short8 kf = *(const short8*)&KsL[(nt * 16 + l15) * 128 + ch * 8];
                            s[nt] = __builtin_amdgcn_mfma_f32_16x16x32_bf16(kf, qf[ks], s[nt], 0, 0, 0);
                        }
                        if (diag && nt == w) {
#pragma unroll
                            for (int r = 0; r < 4; ++r)
                                if (quad * 4 + r > l15) s[nt][r] = -1e30f;
                        }
                    } else {
#pragma unroll
                        for (int r = 0; r < 4; ++r) s[nt][r] = -1e30f;
                    }
                }

                // ---- online softmax: state per lane (qrow = l15), base-2 ----
                float mloc = -1e30f;
#pragma unroll
                for (int nt = 0; nt < 4; ++nt)
#pragma unroll
                    for (int r = 0; r < 4; ++r) mloc = fmaxf(mloc, s[nt][r]);
                mloc = fmaxf(mloc, __shfl_xor(mloc, 16));
                mloc = fmaxf(mloc, __shfl_xor(mloc, 32));
                float mnew = fmaxf(m_i, mloc);
                bool up = __any(mloc > m_i);  // wave-uniform; skip rescale if max unchanged
                float alpha = up ? exp2f(m_i - mnew) : 1.0f;
                float sl = 0.f;
#pragma unroll
                for (int nt = 0; nt < 4; ++nt)
#pragma unroll
                    for (int r = 0; r < 4; ++r) {
                        s[nt][r] = exp2f(s[nt][r] - mnew);
                        sl += s[nt][r];
                    }
                sl += __shfl_xor(sl, 16);
                sl += __shfl_xor(sl, 32);
                l_i = l_i * alpha + sl;
                m_i = mnew;
                if (up) {
#pragma unroll
                    for (int d8 = 0; d8 < 8; ++d8)
#pragma unroll
                        for (int r = 0; r < 4; ++r) acc[d8][r] *= alpha;
                }

                // ---- P -> PsW[qrow=l15][key] (swizzled, paired b32 writes) ----
#pragma unroll
                for (int nt = 0; nt < 4; ++nt)
#pragma unroll
                    for (int rr = 0; rr < 2; ++rr) {
                        int col = nt * 16 + quad * 4 + rr * 2;
                        int ch = (col >> 3) ^ (l15 & 7);
                        __hip_bfloat162 pk;
                        pk.x = __float2bfloat16(s[nt][rr * 2]);
                        pk.y = __float2bfloat16(s[nt][rr * 2 + 1]);
                        *(__hip_bfloat162*)&PsW[l15 * 64 + ch * 8 + (col & 7)] = pk;
                    }
                asm volatile("s_waitcnt lgkmcnt(0)" ::: "memory");

                // ---- O^T += V^T P^T : A=Vt frag, B=P frag ----
                int kkmax = diag ? (w >> 1) + 1 : 2;
#pragma unroll
                for (int kk = 0; kk < 2; ++kk) {
                    if (kk < kkmax) {
                        int chp = (kk * 4 + quad) ^ (l15 & 7);
                        short8 pf = *(const short8*)&PsW[l15 * 64 + chp * 8];
#pragma unroll
                        for (int d8 = 0; d8 < 8; ++d8) {
                            short8 vf = *(const short8*)&VtL[(d8 * 16 + l15) * 64 + chp * 8];
                            acc[d8] = __builtin_amdgcn_mfma_f32_16x16x32_bf16(vf, pf, acc[d8], 0, 0, 0);
                        }
                    }
                }
            }
        }

        // ---- split-KV merge: group1 state folded into group0, then epilogue ----
        __syncthreads();  // loop LDS reads complete everywhere
        if (quad == 0) {
            mlbuf[(wave * 16 + l15) * 2] = m_i;
            mlbuf[(wave * 16 + l15) * 2 + 1] = l_i;
        }
        __syncthreads();
        if (grp == 1) {
            float m_a = mlbuf[(w * 16 + l15) * 2];
            float mm = fmaxf(m_a, m_i);
            float fb = exp2f(m_i - mm);
            float* ob = Obuf + (w * 16 + l15) * 132;
#pragma unroll
            for (int d8 = 0; d8 < 8; ++d8) {
                f32x4 t = acc[d8] * fb;
                *(f32x4*)&ob[d8 * 16 + quad * 4] = t;
            }
        }
        __syncthreads();
        if (grp == 0) {
            float m_b = mlbuf[((w + 4) * 16 + l15) * 2];
            float l_b = mlbuf[((w + 4) * 16 + l15) * 2 + 1];
            float mm = fmaxf(m_i, m_b);
            float fa = exp2f(m_i - mm);
            float fb = exp2f(m_b - mm);
            float lt = l_i * fa + l_b * fb;
            float* ob = Obuf + (w * 16 + l15) * 132;
#pragma unroll
            for (int d8 = 0; d8 < 8; ++d8) {
                f32x4 t = *(const f32x4*)&ob[d8 * 16 + quad * 4];
                acc[d8] = acc[d8] * fa + t;
            }
            float linv = 1.0f / lt;  // per lane (qrow = l15); lt >= diag term > 0

            // ---- epilogue: O^T -> (LDS transpose in K0 region) -> coalesced Y ----
            bf16* ow = (bf16*)smem + w * 2048;  // 16 rows (qrow) x 128 cols (dh), swizzled
#pragma unroll
            for (int d8 = 0; d8 < 8; ++d8)
#pragma unroll
                for (int rr = 0; rr < 2; ++rr) {
                    int colD = d8 * 16 + quad * 4 + rr * 2;
                    int ch = (colD >> 3) ^ (l15 & 7);
                    __hip_bfloat162 o2;
                    o2.x = __float2bfloat16(acc[d8][rr * 2] * linv);
                    o2.y = __float2bfloat16(acc[d8][rr * 2 + 1] * linv);
                    *(__hip_bfloat162*)&ow[l15 * 128 + ch * 8 + (colD & 7)] = o2;
                }
            asm volatile("s_waitcnt lgkmcnt(0)" ::: "memory");
#pragma unroll
            for (int c = 0; c < 4; ++c) {
                int chunk = quad * 4 + c;
                int ch = chunk ^ (l15 & 7);
                short8 ov = *(const short8*)&ow[l15 * 128 + ch * 8];
                *(short8*)&Y[(size_t)(qbase + l15) * DD + h * DHD + chunk * 8] = ov;
            }
        }
        __syncthreads();  // pass-2 staging must not clobber merge/epilogue reads
    }
}

extern "C" void kernel_launch(void* const* d_in, const int* in_sizes, int n_in,
                              void* d_out, int out_size, void* d_ws, size_t ws_size,
                              hipStream_t stream) {
    const float* x = (const float*)d_in[0];
    const float* Wq = (const float*)d_in[1];
    const float* Wk = (const float*)d_in[2];
    const float* Wv = (const float*)d_in[3];
    const float* Wo = (const float*)d_in[4];

    char* ws = (char*)d_ws;
    size_t off = 0;
    auto alloc = [&](size_t bytes) {
        void* p = ws + off;
        off += (bytes + 255) & ~(size_t)255;
        return p;
    };
    bf16* xb = (bf16*)alloc((size_t)TT * DD * 2);
    bf16* Wt = (bf16*)alloc((size_t)NQKV * DD * 2);
    bf16* Wot = (bf16*)alloc((size_t)DD * DD * 2);
    bf16* QKVb = (bf16*)alloc((size_t)TT * NQKV * 2);
    bf16* Qs = (bf16*)alloc((size_t)NH * TT * DHD * 2);
    bf16* Ksb = (bf16*)alloc((size_t)NKV * TT * DHD * 2);
    bf16* Vtb = (bf16*)alloc((size_t)NKV * DHD * TT * 2);
    bf16* Yb = (bf16*)alloc((size_t)TT * DD * 2);

    cast_x_kernel<<<(TT * DD / 4 + 255) / 256, 256, 0, stream>>>(x, xb, TT * DD);
    transpose_cast_all<<<dim3(64, 64, 4), dim3(32, 8), 0, stream>>>(Wq, Wk, Wv, Wo, Wt, Wot);

    gemm_bt_kernel<true><<<dim3(NQKV / 128, TT / 128), 256, 0, stream>>>(xb, Wt, QKVb, TT, NQKV, DD);
    rope_split_kernel<<<TT * 24 / 4, 256, 0, stream>>>(QKVb, Qs, Ksb, Vtb);
    attn_kernel<<<dim3(32, NH), 512, 0, stream>>>(Qs, Ksb, Vtb, Yb);
    gemm_bt_kernel<false><<<dim3(DD / 128, TT / 128), 256, 0, stream>>>(Yb, Wot, d_out, TT, DD, DD);
}

// Round 4
// 400.690 us; speedup vs baseline: 1.2895x; 1.0114x over previous
//
#include <hip/hip_runtime.h>
#include <hip/hip_bf16.h>

#define TT 4096
#define DD 2048
#define NH 16
#define NKV 4
#define DHD 128
#define NQKV 3072

typedef __attribute__((ext_vector_type(8))) short short8;
typedef __attribute__((ext_vector_type(4))) float f32x4;
typedef __hip_bfloat16 bf16;

// async global->LDS, 16B per lane; LDS dest = wave-uniform base + lane*16
#define GLOAD_LDS16(g, l)                                                \
    __builtin_amdgcn_global_load_lds(                                    \
        (const __attribute__((address_space(1))) unsigned int*)(g),      \
        (__attribute__((address_space(3))) unsigned int*)(l), 16, 0, 0)

// ---------------- cast x -> bf16 ----------------
__global__ void cast_x_kernel(const float* __restrict__ x, bf16* __restrict__ xb, int n) {
    int i = (blockIdx.x * blockDim.x + threadIdx.x) * 4;
    if (i >= n) return;
    float4 v = *(const float4*)(x + i);
    xb[i + 0] = __float2bfloat16(v.x);
    xb[i + 1] = __float2bfloat16(v.y);
    xb[i + 2] = __float2bfloat16(v.z);
    xb[i + 3] = __float2bfloat16(v.w);
}

// ---------------- all 4 weight transposes in one launch ----------------
__global__ void transpose_cast_all(const float* __restrict__ Wq, const float* __restrict__ Wk,
                                   const float* __restrict__ Wv, const float* __restrict__ Wo,
                                   bf16* __restrict__ Wt, bf16* __restrict__ Wot) {
    __shared__ float tile[32][33];
    const float* in;
    bf16* out;
    int N, rowOff;
    switch (blockIdx.z) {
        case 0: in = Wq; out = Wt; N = 2048; rowOff = 0; break;
        case 1: in = Wk; out = Wt; N = 512; rowOff = 2048; break;
        case 2: in = Wv; out = Wt; N = 512; rowOff = 2560; break;
        default: in = Wo; out = Wot; N = 2048; rowOff = 0; break;
    }
    int n0 = blockIdx.y * 32;
    if (n0 >= N) return;
    int k0 = blockIdx.x * 32;
    int tx = threadIdx.x, ty = threadIdx.y;
#pragma unroll
    for (int i = 0; i < 4; ++i)
        tile[ty + i * 8][tx] = in[(size_t)(k0 + ty + i * 8) * N + n0 + tx];
    __syncthreads();
#pragma unroll
    for (int i = 0; i < 4; ++i)
        out[(size_t)(rowOff + n0 + ty + i * 8) * 2048 + k0 + tx] = __float2bfloat16(tile[tx][ty + i * 8]);
}

// ---------------- GEMM (m97 recipe + T1 XCD swizzle): A (MxK), Bt (NxK), C (MxN) ----------------
template <bool OUT_BF16>
__global__ __launch_bounds__(256) void gemm_bt_kernel(const bf16* __restrict__ A,
                                                      const bf16* __restrict__ Bt,
                                                      void* __restrict__ C,
                                                      int M, int N, int K) {
    __shared__ bf16 As[128 * 32];
    __shared__ bf16 Bs[128 * 32];
    // XCD-aware swizzle (requires nwg % 8 == 0; grids are 768 and 512 blocks)
    int nwg = gridDim.x * gridDim.y;
    int orig = blockIdx.y * gridDim.x + blockIdx.x;
    int swz = (orig & 7) * (nwg >> 3) + (orig >> 3);
    int bx = swz % gridDim.x, by = swz / gridDim.x;
    int bn0 = bx * 128, bm0 = by * 128;
    int tid = threadIdx.x;
    int wave = tid >> 6, lane = tid & 63, quad = lane >> 4, l15 = lane & 15;
    int wm = (wave >> 1) * 64, wn = (wave & 1) * 64;

    // staging: per wave, 2 insts A (16 rows each) + 2 insts B
    int srow = wave * 32 + (lane >> 2);
    int scol = (lane & 3) * 8;
    const bf16* gA = A + (size_t)(bm0 + srow) * K + scol;
    const bf16* gB = Bt + (size_t)(bn0 + srow) * K + scol;
    bf16* lA = As + srow * 32 + scol;
    bf16* lB = Bs + srow * 32 + scol;

    f32x4 zero = {0.f, 0.f, 0.f, 0.f};
    f32x4 acc[4][4];
#pragma unroll
    for (int i = 0; i < 4; ++i)
#pragma unroll
        for (int j = 0; j < 4; ++j) acc[i][j] = zero;

    for (int k0 = 0; k0 < K; k0 += 32) {
        GLOAD_LDS16(gA + k0, lA);
        GLOAD_LDS16(gA + k0 + (size_t)16 * K, lA + 16 * 32);
        GLOAD_LDS16(gB + k0, lB);
        GLOAD_LDS16(gB + k0 + (size_t)16 * K, lB + 16 * 32);
        __syncthreads();
        short8 af[4], bfr[4];
#pragma unroll
        for (int i = 0; i < 4; ++i) af[i] = *(const short8*)&As[(wm + i * 16 + l15) * 32 + quad * 8];
#pragma unroll
        for (int j = 0; j < 4; ++j) bfr[j] = *(const short8*)&Bs[(wn + j * 16 + l15) * 32 + quad * 8];
#pragma unroll
        for (int i = 0; i < 4; ++i)
#pragma unroll
            for (int j = 0; j < 4; ++j)
                acc[i][j] = __builtin_amdgcn_mfma_f32_16x16x32_bf16(af[i], bfr[j], acc[i][j], 0, 0, 0);
        __syncthreads();
    }
#pragma unroll
    for (int i = 0; i < 4; ++i)
#pragma unroll
        for (int j = 0; j < 4; ++j)
#pragma unroll
            for (int r = 0; r < 4; ++r) {
                int row = bm0 + wm + i * 16 + quad * 4 + r;
                int col = bn0 + wn + j * 16 + l15;
                float v = acc[i][j][r];
                if (OUT_BF16)
                    ((bf16*)C)[(size_t)row * N + col] = __float2bfloat16(v);
                else
                    ((float*)C)[(size_t)row * N + col] = v;
            }
}

// ---------------- RoPE + head split. Q scaled by 1/sqrt(128)*log2(e) ----------------
__global__ void rope_split_kernel(const bf16* __restrict__ QKV, bf16* __restrict__ Qs,
                                  bf16* __restrict__ Ks, bf16* __restrict__ Vt) {
    int slot = blockIdx.x * 4 + (threadIdx.x >> 6);
    int d = threadIdx.x & 63;
    int t = slot / 24, c = slot % 24;
    const bf16* base = QKV + (size_t)t * NQKV;
    int off = (c < 16) ? c * 128 : (c < 20) ? 2048 + (c - 16) * 128 : 2560 + (c - 20) * 128;
    float x1 = __bfloat162float(base[off + d]);
    float x2 = __bfloat162float(base[off + 64 + d]);
    float o1, o2;
    if (c < 20) {
        float invf = __expf((float)d * -0.14391156831f);
        float ang = (float)t * invf;
        float sn = sinf(ang), cs = cosf(ang);
        o1 = x1 * cs - x2 * sn;
        o2 = x1 * sn + x2 * cs;
    } else {
        o1 = x1;
        o2 = x2;
    }
    if (c < 16) {
        const float scale = 0.12751741f;  // 1/sqrt(128) * log2(e)
        o1 *= scale;
        o2 *= scale;
        bf16* dst = Qs + ((size_t)c * TT + t) * DHD;
        dst[d] = __float2bfloat16(o1);
        dst[d + 64] = __float2bfloat16(o2);
    } else if (c < 20) {
        bf16* dst = Ks + ((size_t)(c - 16) * TT + t) * DHD;
        dst[d] = __float2bfloat16(o1);
        dst[d + 64] = __float2bfloat16(o2);
    } else {
        int gg = c - 20;
        Vt[((size_t)gg * DHD + d) * TT + t] = __float2bfloat16(o1);
        Vt[((size_t)gg * DHD + d + 64) * TT + t] = __float2bfloat16(o2);
    }
}

// ---------------- Flash attention: transposed-S, xor-swizzled LDS, split-KV ----------------
// 512 threads = 8 waves: group 0 (waves 0-3) = EVEN k-tiles, group 1 (waves 4-7) = ODD,
// split-K merge per pass. K/V staging via global_load_lds (linear dest + inverse-swizzled
// global source). amdgpu_waves_per_eu(4,4): LDS caps at 2 blocks/CU = 4 waves/SIMD anyway,
// so allow the full 128-VGPR budget -- at 64 VGPRs (live set = acc32+qf16+s16) the compiler
// rematerializes every address each iteration (round-3: VALUBusy 45% vs MfmaUtil 18%).
__global__ __launch_bounds__(512) __attribute__((amdgpu_waves_per_eu(4, 4)))
void attn_kernel(const bf16* __restrict__ Qs,
                 const bf16* __restrict__ Ks,
                 const bf16* __restrict__ Vt,
                 bf16* __restrict__ Y) {
    // layout (bytes):
    //   [0      , 32768 ) K0(64x128 swz) + V0(128x64 swz)   group 0
    //   [32768  , 65536 ) K1 + V1                            group 1
    //   [65536  , 81920 ) P per wave (8 x 16x64 swz)
    // merge-phase aliases (loop LDS dead then, separated by barriers):
    //   Obuf  = [32768, 66560)  f32 [4 pairs][16 qrow][132]  (pad +4 -> 2-way banks)
    //   mlbuf = [80896, 81920)  f32 [8 waves][16 qrow][2]
    __shared__ char smem[81920];
    int h = blockIdx.y, bpair = blockIdx.x, g = h >> 2;
    int tid = threadIdx.x, wave = tid >> 6, lane = tid & 63, quad = lane >> 4, l15 = lane & 15;
    int grp = wave >> 2;   // 0: even k-tiles, 1: odd k-tiles
    int w = wave & 3;      // q-subtile (16 rows) within the 64-row Q tile
    int gtid = tid & 255;  // tid within group

    bf16* KsL = (bf16*)(smem + grp * 32768);          // row=key(64), chunk c holds global c^(row&15)
    bf16* VtL = (bf16*)(smem + grp * 32768 + 16384);  // row=dh(128), chunk c holds global c^(row&7)
    bf16* PsW = (bf16*)(smem + 65536) + wave * (16 * 64);
    float* Obuf = (float*)(smem + 32768);
    float* mlbuf = (float*)(smem + 80896);

    const bf16* kg = Ks + (size_t)g * TT * DHD;
    const bf16* vg = Vt + (size_t)g * DHD * TT;
    f32x4 zero = {0.f, 0.f, 0.f, 0.f};

    // loop-invariant per-lane staging geometry (inverse-swizzled global offsets, linear LDS)
    int koffl[4], voffl[4], ldsl[4];
#pragma unroll
    for (int r = 0; r < 4; ++r) {
        int idx = r * 256 + gtid;
        int krow = idx >> 4, kch = (idx & 15) ^ (krow & 15);
        koffl[r] = krow * DHD + kch * 8;
        int vrow = idx >> 3, vch = (idx & 7) ^ (vrow & 7);
        voffl[r] = vrow * TT + vch * 8;
        ldsl[r] = idx * 8;  // elements; *2B = r*4096 + wave*1024 + lane*16 (linear)
    }

    for (int pass = 0; pass < 2; ++pass) {
        int qt = (pass == 0) ? bpair : 63 - bpair;
        int qbase = qt * 64 + w * 16;

        short8 qf[4];
        const bf16* qptr = Qs + ((size_t)h * TT + qbase + l15) * DHD + quad * 8;
#pragma unroll
        for (int ks = 0; ks < 4; ++ks) qf[ks] = *(const short8*)(qptr + ks * 32);

        f32x4 acc[8];
#pragma unroll
        for (int i = 0; i < 8; ++i) acc[i] = zero;
        float m_i = -1e30f, l_i = 0.f;

        const bf16* kSrc = kg + (size_t)grp * 64 * DHD;  // k-tile kt = it*2+grp
        const bf16* vSrc = vg + grp * 64;
        int nIter = (qt >> 1) + 1;
        for (int it = 0; it < nIter; ++it) {
            int kt = it * 2 + grp;
            bool active = (kt <= qt);
            bool diag = (kt == qt);
            __syncthreads();  // prior iter LDS reads / merge-phase reads complete
            if (active) {
#pragma unroll
                for (int r = 0; r < 4; ++r) {
                    GLOAD_LDS16(kSrc + koffl[r], KsL + ldsl[r]);
                    GLOAD_LDS16(vSrc + voffl[r], VtL + ldsl[r]);
                }
            }
            kSrc += 128 * DHD;  // advance 2 k-tiles
            vSrc += 128;
            __syncthreads();  // drains vmcnt -> K/V visible to whole group

            if (active) {
                // ---- S^T = K Q^T : A=K frag, B=Q frag ----
                f32x4 s[4];
                __builtin_amdgcn_s_setprio(1);
#pragma unroll
                for (int nt = 0; nt < 4; ++nt) {
                    if (!diag || nt <= w) {
                        s[nt] = zero;
#pragma unroll
                        for (int ks = 0; ks < 4; ++ks) {
                            int ch = (ks * 4 + quad) ^ l15;
                            short8 kf = *(const short8*)&KsL[(nt * 16 + l15) * 128 + ch * 8];
                            s[nt] = __builtin_amdgcn_mfma_f32_16x16x32_bf16(kf, qf[ks], s[nt], 0, 0, 0);
                        }
                        if (diag && nt == w) {
#pragma unroll
                            for (int r = 0; r < 4; ++r)
                                if (quad * 4 + r > l15) s[nt][r] = -1e30f;
                        }
                    } else {
#pragma unroll
                        for (int r = 0; r < 4; ++r) s[nt][r] = -1e30f;
                    }
                }
                __builtin_amdgcn_s_setprio(0);

                // ---- online softmax: state per lane (qrow = l15), base-2 ----
                float mloc = -1e30f;
#pragma unroll
                for (int nt = 0; nt < 4; ++nt)
#pragma unroll
                    for (int r = 0; r < 4; ++r) mloc = fmaxf(mloc, s[nt][r]);
                mloc = fmaxf(mloc, __shfl_xor(mloc, 16));
                mloc = fmaxf(mloc, __shfl_xor(mloc, 32));
                float mnew = fmaxf(m_i, mloc);
                bool up = __any(mloc > m_i);  // wave-uniform; skip rescale if max unchanged
                float alpha = up ? exp2f(m_i - mnew) : 1.0f;
                float sl = 0.f;
#pragma unroll
                for (int nt = 0; nt < 4; ++nt)
#pragma unroll
                    for (int r = 0; r < 4; ++r) {
                        s[nt][r] = exp2f(s[nt][r] - mnew);
                        sl += s[nt][r];
                    }
                sl += __shfl_xor(sl, 16);
                sl += __shfl_xor(sl, 32);
                l_i = l_i * alpha + sl;
                m_i = mnew;
                if (up) {
#pragma unroll
                    for (int d8 = 0; d8 < 8; ++d8)
#pragma unroll
                        for (int r = 0; r < 4; ++r) acc[d8][r] *= alpha;
                }

                // ---- P -> PsW[qrow=l15][key] (swizzled, paired b32 writes) ----
#pragma unroll
                for (int nt = 0; nt < 4; ++nt)
#pragma unroll
                    for (int rr = 0; rr < 2; ++rr) {
                        int col = nt * 16 + quad * 4 + rr * 2;
                        int ch = (col >> 3) ^ (l15 & 7);
                        __hip_bfloat162 pk;
                        pk.x = __float2bfloat16(s[nt][rr * 2]);
                        pk.y = __float2bfloat16(s[nt][rr * 2 + 1]);
                        *(__hip_bfloat162*)&PsW[l15 * 64 + ch * 8 + (col & 7)] = pk;
                    }
                asm volatile("s_waitcnt lgkmcnt(0)" ::: "memory");

                // ---- O^T += V^T P^T : A=Vt frag, B=P frag ----
                int kkmax = diag ? (w >> 1) + 1 : 2;
                __builtin_amdgcn_s_setprio(1);
#pragma unroll
                for (int kk = 0; kk < 2; ++kk) {
                    if (kk < kkmax) {
                        int chp = (kk * 4 + quad) ^ (l15 & 7);
                        short8 pf = *(const short8*)&PsW[l15 * 64 + chp * 8];
#pragma unroll
                        for (int d8 = 0; d8 < 8; ++d8) {
                            short8 vf = *(const short8*)&VtL[(d8 * 16 + l15) * 64 + chp * 8];
                            acc[d8] = __builtin_amdgcn_mfma_f32_16x16x32_bf16(vf, pf, acc[d8], 0, 0, 0);
                        }
                    }
                }
                __builtin_amdgcn_s_setprio(0);
            }
        }

        // ---- split-KV merge: group1 state folded into group0, then epilogue ----
        __syncthreads();  // loop LDS reads complete everywhere
        if (quad == 0) {
            mlbuf[(wave * 16 + l15) * 2] = m_i;
            mlbuf[(wave * 16 + l15) * 2 + 1] = l_i;
        }
        __syncthreads();
        if (grp == 1) {
            float m_a = mlbuf[(w * 16 + l15) * 2];
            float mm = fmaxf(m_a, m_i);
            float fb = exp2f(m_i - mm);
            float* ob = Obuf + (w * 16 + l15) * 132;
#pragma unroll
            for (int d8 = 0; d8 < 8; ++d8) {
                f32x4 t = acc[d8] * fb;
                *(f32x4*)&ob[d8 * 16 + quad * 4] = t;
            }
        }
        __syncthreads();
        if (grp == 0) {
            float m_b = mlbuf[((w + 4) * 16 + l15) * 2];
            float l_b = mlbuf[((w + 4) * 16 + l15) * 2 + 1];
            float mm = fmaxf(m_i, m_b);
            float fa = exp2f(m_i - mm);
            float fb = exp2f(m_b - mm);
            float lt = l_i * fa + l_b * fb;
            float* ob = Obuf + (w * 16 + l15) * 132;
#pragma unroll
            for (int d8 = 0; d8 < 8; ++d8) {
                f32x4 t = *(const f32x4*)&ob[d8 * 16 + quad * 4];
                acc[d8] = acc[d8] * fa + t;
            }
            float linv = 1.0f / lt;  // per lane (qrow = l15); lt >= diag term > 0

            // ---- epilogue: O^T -> (LDS transpose in K0 region) -> coalesced Y ----
            bf16* ow = (bf16*)smem + w * 2048;  // 16 rows (qrow) x 128 cols (dh), swizzled
#pragma unroll
            for (int d8 = 0; d8 < 8; ++d8)
#pragma unroll
                for (int rr = 0; rr < 2; ++rr) {
                    int colD = d8 * 16 + quad * 4 + rr * 2;
                    int ch = (colD >> 3) ^ (l15 & 7);
                    __hip_bfloat162 o2;
                    o2.x = __float2bfloat16(acc[d8][rr * 2] * linv);
                    o2.y = __float2bfloat16(acc[d8][rr * 2 + 1] * linv);
                    *(__hip_bfloat162*)&ow[l15 * 128 + ch * 8 + (colD & 7)] = o2;
                }
            asm volatile("s_waitcnt lgkmcnt(0)" ::: "memory");
#pragma unroll
            for (int c = 0; c < 4; ++c) {
                int chunk = quad * 4 + c;
                int ch = chunk ^ (l15 & 7);
                short8 ov = *(const short8*)&ow[l15 * 128 + ch * 8];
                *(short8*)&Y[(size_t)(qbase + l15) * DD + h * DHD + chunk * 8] = ov;
            }
        }
        __syncthreads();  // pass-2 staging must not clobber merge/epilogue reads
    }
}

extern "C" void kernel_launch(void* const* d_in, const int* in_sizes, int n_in,
                              void* d_out, int out_size, void* d_ws, size_t ws_size,
                              hipStream_t stream) {
    const float* x = (const float*)d_in[0];
    const float* Wq = (const float*)d_in[1];
    const float* Wk = (const float*)d_in[2];
    const float* Wv = (const float*)d_in[3];
    const float* Wo = (const float*)d_in[4];

    char* ws = (char*)d_ws;
    size_t off = 0;
    auto alloc = [&](size_t bytes) {
        void* p = ws + off;
        off += (bytes + 255) & ~(size_t)255;
        return p;
    };
    bf16* xb = (bf16*)alloc((size_t)TT * DD * 2);
    bf16* Wt = (bf16*)alloc((size_t)NQKV * DD * 2);
    bf16* Wot = (bf16*)alloc((size_t)DD * DD * 2);
    bf16* QKVb = (bf16*)alloc((size_t)TT * NQKV * 2);
    bf16* Qs = (bf16*)alloc((size_t)NH * TT * DHD * 2);
    bf16* Ksb = (bf16*)alloc((size_t)NKV * TT * DHD * 2);
    bf16* Vtb = (bf16*)alloc((size_t)NKV * DHD * TT * 2);
    bf16* Yb = (bf16*)alloc((size_t)TT * DD * 2);

    cast_x_kernel<<<(TT * DD / 4 + 255) / 256, 256, 0, stream>>>(x, xb, TT * DD);
    transpose_cast_all<<<dim3(64, 64, 4), dim3(32, 8), 0, stream>>>(Wq, Wk, Wv, Wo, Wt, Wot);

    gemm_bt_kernel<true><<<dim3(NQKV / 128, TT / 128), 256, 0, stream>>>(xb, Wt, QKVb, TT, NQKV, DD);
    rope_split_kernel<<<TT * 24 / 4, 256, 0, stream>>>(QKVb, Qs, Ksb, Vtb);
    attn_kernel<<<dim3(32, NH), 512, 0, stream>>>(Qs, Ksb, Vtb, Yb);
    gemm_bt_kernel<false><<<dim3(DD / 128, TT / 128), 256, 0, stream>>>(Yb, Wot, d_out, TT, DD, DD);
}

// Round 5
// 394.906 us; speedup vs baseline: 1.3084x; 1.0146x over previous
//
#include <hip/hip_runtime.h>
#include <hip/hip_bf16.h>

#define TT 4096
#define DD 2048
#define NH 16
#define NKV 4
#define DHD 128
#define NQKV 3072

typedef __attribute__((ext_vector_type(8))) short short8;
typedef __attribute__((ext_vector_type(4))) float f32x4;
typedef __hip_bfloat16 bf16;

// async global->LDS, 16B per lane; LDS dest = wave-uniform base + lane*16
#define GLOAD_LDS16(g, l)                                                \
    __builtin_amdgcn_global_load_lds(                                    \
        (const __attribute__((address_space(1))) unsigned int*)(g),      \
        (__attribute__((address_space(3))) unsigned int*)(l), 16, 0, 0)

// ---------------- cast x -> bf16 ----------------
__global__ void cast_x_kernel(const float* __restrict__ x, bf16* __restrict__ xb, int n) {
    int i = (blockIdx.x * blockDim.x + threadIdx.x) * 4;
    if (i >= n) return;
    float4 v = *(const float4*)(x + i);
    xb[i + 0] = __float2bfloat16(v.x);
    xb[i + 1] = __float2bfloat16(v.y);
    xb[i + 2] = __float2bfloat16(v.z);
    xb[i + 3] = __float2bfloat16(v.w);
}

// ---------------- all 4 weight transposes in one launch ----------------
__global__ void transpose_cast_all(const float* __restrict__ Wq, const float* __restrict__ Wk,
                                   const float* __restrict__ Wv, const float* __restrict__ Wo,
                                   bf16* __restrict__ Wt, bf16* __restrict__ Wot) {
    __shared__ float tile[32][33];
    const float* in;
    bf16* out;
    int N, rowOff;
    switch (blockIdx.z) {
        case 0: in = Wq; out = Wt; N = 2048; rowOff = 0; break;
        case 1: in = Wk; out = Wt; N = 512; rowOff = 2048; break;
        case 2: in = Wv; out = Wt; N = 512; rowOff = 2560; break;
        default: in = Wo; out = Wot; N = 2048; rowOff = 0; break;
    }
    int n0 = blockIdx.y * 32;
    if (n0 >= N) return;
    int k0 = blockIdx.x * 32;
    int tx = threadIdx.x, ty = threadIdx.y;
#pragma unroll
    for (int i = 0; i < 4; ++i)
        tile[ty + i * 8][tx] = in[(size_t)(k0 + ty + i * 8) * N + n0 + tx];
    __syncthreads();
#pragma unroll
    for (int i = 0; i < 4; ++i)
        out[(size_t)(rowOff + n0 + ty + i * 8) * 2048 + k0 + tx] = __float2bfloat16(tile[tx][ty + i * 8]);
}

// ---------------- GEMM (m97 recipe + T1 XCD swizzle): A (MxK), Bt (NxK), C (MxN) ----------------
template <bool OUT_BF16>
__global__ __launch_bounds__(256) void gemm_bt_kernel(const bf16* __restrict__ A,
                                                      const bf16* __restrict__ Bt,
                                                      void* __restrict__ C,
                                                      int M, int N, int K) {
    __shared__ bf16 As[128 * 32];
    __shared__ bf16 Bs[128 * 32];
    // XCD-aware swizzle (requires nwg % 8 == 0; grids are 768 and 512 blocks)
    int nwg = gridDim.x * gridDim.y;
    int orig = blockIdx.y * gridDim.x + blockIdx.x;
    int swz = (orig & 7) * (nwg >> 3) + (orig >> 3);
    int bx = swz % gridDim.x, by = swz / gridDim.x;
    int bn0 = bx * 128, bm0 = by * 128;
    int tid = threadIdx.x;
    int wave = tid >> 6, lane = tid & 63, quad = lane >> 4, l15 = lane & 15;
    int wm = (wave >> 1) * 64, wn = (wave & 1) * 64;

    // staging: per wave, 2 insts A (16 rows each) + 2 insts B
    int srow = wave * 32 + (lane >> 2);
    int scol = (lane & 3) * 8;
    const bf16* gA = A + (size_t)(bm0 + srow) * K + scol;
    const bf16* gB = Bt + (size_t)(bn0 + srow) * K + scol;
    bf16* lA = As + srow * 32 + scol;
    bf16* lB = Bs + srow * 32 + scol;

    f32x4 zero = {0.f, 0.f, 0.f, 0.f};
    f32x4 acc[4][4];
#pragma unroll
    for (int i = 0; i < 4; ++i)
#pragma unroll
        for (int j = 0; j < 4; ++j) acc[i][j] = zero;

    for (int k0 = 0; k0 < K; k0 += 32) {
        GLOAD_LDS16(gA + k0, lA);
        GLOAD_LDS16(gA + k0 + (size_t)16 * K, lA + 16 * 32);
        GLOAD_LDS16(gB + k0, lB);
        GLOAD_LDS16(gB + k0 + (size_t)16 * K, lB + 16 * 32);
        __syncthreads();
        short8 af[4], bfr[4];
#pragma unroll
        for (int i = 0; i < 4; ++i) af[i] = *(const short8*)&As[(wm + i * 16 + l15) * 32 + quad * 8];
#pragma unroll
        for (int j = 0; j < 4; ++j) bfr[j] = *(const short8*)&Bs[(wn + j * 16 + l15) * 32 + quad * 8];
#pragma unroll
        for (int i = 0; i < 4; ++i)
#pragma unroll
            for (int j = 0; j < 4; ++j)
                acc[i][j] = __builtin_amdgcn_mfma_f32_16x16x32_bf16(af[i], bfr[j], acc[i][j], 0, 0, 0);
        __syncthreads();
    }
#pragma unroll
    for (int i = 0; i < 4; ++i)
#pragma unroll
        for (int j = 0; j < 4; ++j)
#pragma unroll
            for (int r = 0; r < 4; ++r) {
                int row = bm0 + wm + i * 16 + quad * 4 + r;
                int col = bn0 + wn + j * 16 + l15;
                float v = acc[i][j][r];
                if (OUT_BF16)
                    ((bf16*)C)[(size_t)row * N + col] = __float2bfloat16(v);
                else
                    ((float*)C)[(size_t)row * N + col] = v;
            }
}

// ---------------- RoPE + head split. Q scaled by 1/sqrt(128)*log2(e) ----------------
// V is written ROW-major (coalesced); transpose_v_kernel produces Vt afterward.
__global__ void rope_split_kernel(const bf16* __restrict__ QKV, bf16* __restrict__ Qs,
                                  bf16* __restrict__ Ks, bf16* __restrict__ Vr) {
    int slot = blockIdx.x * 4 + (threadIdx.x >> 6);
    int d = threadIdx.x & 63;
    int t = slot / 24, c = slot % 24;
    const bf16* base = QKV + (size_t)t * NQKV;
    int off = (c < 16) ? c * 128 : (c < 20) ? 2048 + (c - 16) * 128 : 2560 + (c - 20) * 128;
    float x1 = __bfloat162float(base[off + d]);
    float x2 = __bfloat162float(base[off + 64 + d]);
    float o1, o2;
    if (c < 20) {
        float invf = __expf((float)d * -0.14391156831f);
        float ang = (float)t * invf;
        float sn = sinf(ang), cs = cosf(ang);
        o1 = x1 * cs - x2 * sn;
        o2 = x1 * sn + x2 * cs;
    } else {
        o1 = x1;
        o2 = x2;
    }
    if (c < 16) {
        const float scale = 0.12751741f;  // 1/sqrt(128) * log2(e)
        o1 *= scale;
        o2 *= scale;
        bf16* dst = Qs + ((size_t)c * TT + t) * DHD;
        dst[d] = __float2bfloat16(o1);
        dst[d + 64] = __float2bfloat16(o2);
    } else if (c < 20) {
        bf16* dst = Ks + ((size_t)(c - 16) * TT + t) * DHD;
        dst[d] = __float2bfloat16(o1);
        dst[d + 64] = __float2bfloat16(o2);
    } else {
        int gg = c - 20;
        bf16* dst = Vr + ((size_t)gg * TT + t) * DHD;  // coalesced row-major write
        dst[d] = __float2bfloat16(o1);
        dst[d + 64] = __float2bfloat16(o2);
    }
}

// ---------------- V row-major -> Vt [g][dh][t] via LDS tiles (coalesced both sides) ----------
__global__ void transpose_v_kernel(const bf16* __restrict__ Vr, bf16* __restrict__ Vt) {
    __shared__ short tile[64][80];  // 64 t-rows x 64 dh-cols, padded to 80 (160B rows, 16B-aligned)
    int g = blockIdx.z;
    int t0 = blockIdx.x * 64, d0 = blockIdx.y * 64;
    int tid = threadIdx.x;  // 256
#pragma unroll
    for (int i = 0; i < 2; ++i) {
        int lin = i * 2048 + tid * 8;
        int r = lin >> 6, c = lin & 63;  // r = t row, c = dh col
        *(short8*)&tile[r][c] = *(const short8*)(Vr + ((size_t)g * TT + t0 + r) * DHD + d0 + c);
    }
    __syncthreads();
#pragma unroll
    for (int i = 0; i < 2; ++i) {
        int lin = i * 2048 + tid * 8;
        int r = lin >> 6, c = lin & 63;  // r = dh row, c = t col
        short8 v;
#pragma unroll
        for (int j = 0; j < 8; ++j) v[j] = tile[c + j][r];
        *(short8*)(Vt + ((size_t)g * DHD + d0 + r) * TT + t0 + c) = v;
    }
}

// ---------------- Flash attention: split-KV, KVBLK=32, double-buffered 2-phase pipeline ----
// 512 threads = 8 waves: group 0 (waves 0-3) = EVEN 32-key tiles, group 1 = ODD; split-K
// merge per pass. Per iteration: issue next tile's global_load_lds FIRST, then compute the
// current tile, then ONE __syncthreads() (its vmcnt drain lands after ~full compute phase --
// latency hidden; round-4's structure drained vmcnt immediately after issue, 2 barriers/tile).
__global__ __launch_bounds__(512, 4) void attn_kernel(const bf16* __restrict__ Qs,
                                                      const bf16* __restrict__ Ks,
                                                      const bf16* __restrict__ Vt,
                                                      bf16* __restrict__ Y) {
    // layout (bytes):
    //   grp*32768 + buf*8192          : K[grp][buf] 32key x 128dh   (chunk c holds global c^(row&15))
    //   grp*32768 + 16384 + buf*8192  : V[grp][buf] 128dh x 32key   (chunk c holds global c^((row>>1)&3))
    //   65536 + wave*1024             : P 16qrow x 32key per wave   (chunk c at c^((l15>>1)&3))
    //   merge aliases: Obuf f32 [4][16][132] at 32768; mlbuf f32 [8][16][2] at 73728
    __shared__ __attribute__((aligned(16))) char smem[74752];
    int h = blockIdx.y, bpair = blockIdx.x, g = h >> 2;
    int tid = threadIdx.x, wave = tid >> 6, lane = tid & 63, quad = lane >> 4, l15 = lane & 15;
    int grp = wave >> 2;   // 0: even k-tiles, 1: odd k-tiles
    int w = wave & 3;      // q-subtile (16 rows) within the 64-row Q tile
    int gtid = tid & 255;  // tid within group

    char* Kbase = smem + grp * 32768;
    bf16* PsW = (bf16*)(smem + 65536 + wave * 1024);
    float* Obuf = (float*)(smem + 32768);
    float* mlbuf = (float*)(smem + 73728);

    const bf16* kg = Ks + (size_t)g * TT * DHD;
    const bf16* vg = Vt + (size_t)g * DHD * TT;
    f32x4 zero = {0.f, 0.f, 0.f, 0.f};

    // loop-invariant per-lane staging geometry (inverse-swizzled global offsets, linear LDS)
    int kOff[2], vOff[2], lOff[2];
#pragma unroll
    for (int r = 0; r < 2; ++r) {
        int idx = r * 256 + gtid;  // 0..511 16B-chunks
        int krow = idx >> 4;       // 32 rows x 16 chunks
        kOff[r] = krow * DHD + ((idx & 15) ^ (krow & 15)) * 8;
        int vrow = idx >> 2;       // 128 rows x 4 chunks
        vOff[r] = vrow * TT + ((idx & 3) ^ ((vrow >> 1) & 3)) * 8;
        lOff[r] = idx * 8;         // elements; linear
    }
    int fsw = (l15 >> 1) & 3;  // V/P read swizzle term

    for (int pass = 0; pass < 2; ++pass) {
        int qt = (pass == 0) ? bpair : 63 - bpair;
        int qbase = qt * 64 + w * 16;

        short8 qf[4];
        const bf16* qptr = Qs + ((size_t)h * TT + qbase + l15) * DHD + quad * 8;
#pragma unroll
        for (int ks = 0; ks < 4; ++ks) qf[ks] = *(const short8*)(qptr + ks * 32);

        f32x4 acc[8];
#pragma unroll
        for (int i = 0; i < 8; ++i) acc[i] = zero;
        float m_i = -1e30f, l_i = 0.f;

        const bf16* kS = kg + (size_t)(grp * 32) * DHD;  // tile j: kt = 2j+grp
        const bf16* vS = vg + grp * 32;
        int nIter = qt + 1;

        // prologue: stage tile 0 into buf 0
#pragma unroll
        for (int r = 0; r < 2; ++r) {
            GLOAD_LDS16(kS + kOff[r], (bf16*)Kbase + lOff[r]);
            GLOAD_LDS16(vS + vOff[r], (bf16*)(Kbase + 16384) + lOff[r]);
        }
        __syncthreads();

        int boff = 0;
        for (int j = 0; j < nIter; ++j) {
            int kt = 2 * j + grp;
            // ---- issue next tile's loads into the other buffer (async, before compute) ----
            if (j + 1 < nIter) {
#pragma unroll
                for (int r = 0; r < 2; ++r) {
                    GLOAD_LDS16(kS + 64 * DHD + kOff[r], (bf16*)(Kbase + (boff ^ 8192)) + lOff[r]);
                    GLOAD_LDS16(vS + 64 + vOff[r], (bf16*)(Kbase + 16384 + (boff ^ 8192)) + lOff[r]);
                }
            }
            const bf16* Kl = (const bf16*)(Kbase + boff);
            const bf16* Vl = (const bf16*)(Kbase + 16384 + boff);
            int dbase = 2 * kt - 4 * qt - w;  // subtile offset for nt=0: <0 full, ==0 diag, >0 masked
            if (dbase <= 0) {
                // ---- S^T = K Q^T : A=K frag, B=Q frag ----
                f32x4 s[2];
                __builtin_amdgcn_s_setprio(1);
#pragma unroll
                for (int nt = 0; nt < 2; ++nt) {
                    int dnt = dbase + nt;
                    if (dnt <= 0) {
                        s[nt] = zero;
#pragma unroll
                        for (int ks = 0; ks < 4; ++ks) {
                            int ch = (ks * 4 + quad) ^ l15;
                            short8 kf = *(const short8*)&Kl[(nt * 16 + l15) * 128 + ch * 8];
                            s[nt] = __builtin_amdgcn_mfma_f32_16x16x32_bf16(kf, qf[ks], s[nt], 0, 0, 0);
                        }
                        if (dnt == 0) {
#pragma unroll
                            for (int r = 0; r < 4; ++r)
                                if (quad * 4 + r > l15) s[nt][r] = -1e30f;
                        }
                    } else {
#pragma unroll
                        for (int r = 0; r < 4; ++r) s[nt][r] = -1e30f;
                    }
                }
                __builtin_amdgcn_s_setprio(0);

                // ---- online softmax: state per lane (qrow = l15), base-2 ----
                float mloc = -1e30f;
#pragma unroll
                for (int nt = 0; nt < 2; ++nt)
#pragma unroll
                    for (int r = 0; r < 4; ++r) mloc = fmaxf(mloc, s[nt][r]);
                mloc = fmaxf(mloc, __shfl_xor(mloc, 16));
                mloc = fmaxf(mloc, __shfl_xor(mloc, 32));
                float mnew = fmaxf(m_i, mloc);
                bool up = __any(mloc > m_i);  // wave-uniform; skip rescale if max unchanged
                float alpha = up ? exp2f(m_i - mnew) : 1.0f;
                float sl = 0.f;
#pragma unroll
                for (int nt = 0; nt < 2; ++nt)
#pragma unroll
                    for (int r = 0; r < 4; ++r) {
                        s[nt][r] = exp2f(s[nt][r] - mnew);
                        sl += s[nt][r];
                    }
                sl += __shfl_xor(sl, 16);
                sl += __shfl_xor(sl, 32);
                l_i = l_i * alpha + sl;
                m_i = mnew;
                if (up) {
#pragma unroll
                    for (int d8 = 0; d8 < 8; ++d8)
#pragma unroll
                        for (int r = 0; r < 4; ++r) acc[d8][r] *= alpha;
                }

                // ---- P -> PsW[qrow=l15][key 0..31] (swizzled, paired b32 writes) ----
#pragma unroll
                for (int nt = 0; nt < 2; ++nt)
#pragma unroll
                    for (int rr = 0; rr < 2; ++rr) {
                        int col = nt * 16 + quad * 4 + rr * 2;
                        int ch = (col >> 3) ^ fsw;
                        __hip_bfloat162 pk;
                        pk.x = __float2bfloat16(s[nt][rr * 2]);
                        pk.y = __float2bfloat16(s[nt][rr * 2 + 1]);
                        *(__hip_bfloat162*)&PsW[l15 * 32 + ch * 8 + (col & 7)] = pk;
                    }
                asm volatile("s_waitcnt lgkmcnt(0)" ::: "memory");

                // ---- O^T += V^T P^T : A=Vt frag, B=P frag ----
                int chp = quad ^ fsw;
                short8 pf = *(const short8*)&PsW[l15 * 32 + chp * 8];
                __builtin_amdgcn_s_setprio(1);
#pragma unroll
                for (int d8 = 0; d8 < 8; ++d8) {
                    short8 vf = *(const short8*)&Vl[(d8 * 16 + l15) * 32 + chp * 8];
                    acc[d8] = __builtin_amdgcn_mfma_f32_16x16x32_bf16(vf, pf, acc[d8], 0, 0, 0);
                }
                __builtin_amdgcn_s_setprio(0);
            }
            __syncthreads();  // next buffer ready (loads issued ~whole compute ago) + reads done
            boff ^= 8192;
            kS += 64 * DHD;
            vS += 64;
        }

        // ---- split-KV merge: group1 state folded into group0, then epilogue ----
        if (quad == 0) {
            mlbuf[(wave * 16 + l15) * 2] = m_i;
            mlbuf[(wave * 16 + l15) * 2 + 1] = l_i;
        }
        __syncthreads();
        if (grp == 1) {
            float m_a = mlbuf[(w * 16 + l15) * 2];
            float mm = fmaxf(m_a, m_i);
            float fb = exp2f(m_i - mm);
            float* ob = Obuf + (w * 16 + l15) * 132;
#pragma unroll
            for (int d8 = 0; d8 < 8; ++d8) {
                f32x4 t = acc[d8] * fb;
                *(f32x4*)&ob[d8 * 16 + quad * 4] = t;
            }
        }
        __syncthreads();
        if (grp == 0) {
            float m_b = mlbuf[((w + 4) * 16 + l15) * 2];
            float l_b = mlbuf[((w + 4) * 16 + l15) * 2 + 1];
            float mm = fmaxf(m_i, m_b);
            float fa = exp2f(m_i - mm);
            float fb = exp2f(m_b - mm);
            float lt = l_i * fa + l_b * fb;
            float* ob = Obuf + (w * 16 + l15) * 132;
#pragma unroll
            for (int d8 = 0; d8 < 8; ++d8) {
                f32x4 t = *(const f32x4*)&ob[d8 * 16 + quad * 4];
                acc[d8] = acc[d8] * fa + t;
            }
            float linv = 1.0f / lt;  // per lane (qrow = l15); lt >= diag term > 0

            // ---- epilogue: O^T -> (LDS transpose in dead K0 region) -> coalesced Y ----
            bf16* ow = (bf16*)smem + w * 2048;  // 16 rows (qrow) x 128 cols (dh), swizzled
#pragma unroll
            for (int d8 = 0; d8 < 8; ++d8)
#pragma unroll
                for (int rr = 0; rr < 2; ++rr) {
                    int colD = d8 * 16 + quad * 4 + rr * 2;
                    int ch = (colD >> 3) ^ (l15 & 7);
                    __hip_bfloat162 o2;
                    o2.x = __float2bfloat16(acc[d8][rr * 2] * linv);
                    o2.y = __float2bfloat16(acc[d8][rr * 2 + 1] * linv);
                    *(__hip_bfloat162*)&ow[l15 * 128 + ch * 8 + (colD & 7)] = o2;
                }
            asm volatile("s_waitcnt lgkmcnt(0)" ::: "memory");
#pragma unroll
            for (int c = 0; c < 4; ++c) {
                int chunk = quad * 4 + c;
                int ch = chunk ^ (l15 & 7);
                short8 ov = *(const short8*)&ow[l15 * 128 + ch * 8];
                *(short8*)&Y[(size_t)(qbase + l15) * DD + h * DHD + chunk * 8] = ov;
            }
        }
        __syncthreads();  // pass-2 staging must not clobber merge/epilogue reads
    }
}

extern "C" void kernel_launch(void* const* d_in, const int* in_sizes, int n_in,
                              void* d_out, int out_size, void* d_ws, size_t ws_size,
                              hipStream_t stream) {
    const float* x = (const float*)d_in[0];
    const float* Wq = (const float*)d_in[1];
    const float* Wk = (const float*)d_in[2];
    const float* Wv = (const float*)d_in[3];
    const float* Wo = (const float*)d_in[4];

    char* ws = (char*)d_ws;
    size_t off = 0;
    auto alloc = [&](size_t bytes) {
        void* p = ws + off;
        off += (bytes + 255) & ~(size_t)255;
        return p;
    };
    bf16* xb = (bf16*)alloc((size_t)TT * DD * 2);
    bf16* Wt = (bf16*)alloc((size_t)NQKV * DD * 2);
    bf16* Wot = (bf16*)alloc((size_t)DD * DD * 2);
    bf16* QKVb = (bf16*)alloc((size_t)TT * NQKV * 2);
    bf16* Qs = (bf16*)alloc((size_t)NH * TT * DHD * 2);
    bf16* Ksb = (bf16*)alloc((size_t)NKV * TT * DHD * 2);
    bf16* Vrb = (bf16*)alloc((size_t)NKV * TT * DHD * 2);
    bf16* Vtb = (bf16*)alloc((size_t)NKV * DHD * TT * 2);
    bf16* Yb = (bf16*)alloc((size_t)TT * DD * 2);

    cast_x_kernel<<<(TT * DD / 4 + 255) / 256, 256, 0, stream>>>(x, xb, TT * DD);
    transpose_cast_all<<<dim3(64, 64, 4), dim3(32, 8), 0, stream>>>(Wq, Wk, Wv, Wo, Wt, Wot);

    gemm_bt_kernel<true><<<dim3(NQKV / 128, TT / 128), 256, 0, stream>>>(xb, Wt, QKVb, TT, NQKV, DD);
    rope_split_kernel<<<TT * 24 / 4, 256, 0, stream>>>(QKVb, Qs, Ksb, Vrb);
    transpose_v_kernel<<<dim3(TT / 64, DHD / 64, NKV), 256, 0, stream>>>(Vrb, Vtb);
    attn_kernel<<<dim3(32, NH), 512, 0, stream>>>(Qs, Ksb, Vtb, Yb);
    gemm_bt_kernel<false><<<dim3(DD / 128, TT / 128), 256, 0, stream>>>(Yb, Wot, d_out, TT, DD, DD);
}